// Round 11
// baseline (134.404 us; speedup 1.0000x reference)
//
#include <hip/hip_runtime.h>
#include <math.h>

#define NB 16
#define CF 64
#define LL 16384
#define GG 8
#define NH 2
#define CHN 64
#define NCH 256
#define NGRP 16

static constexpr size_t OFF_GT = 0;
static constexpr size_t OFF_U2 = OFF_GT + (size_t)NB*LL*GG;
static constexpr size_t OFF_AC = OFF_U2 + (size_t)NB*NCH*256;
static constexpr size_t OFF_PH = OFF_AC + (size_t)NB*NCH*NH;
static constexpr size_t OFF_CP = OFF_PH + (size_t)NB*NCH*256;
static constexpr size_t OFF_UG = OFF_CP + (size_t)NB*NCH*NH;
static constexpr size_t OFF_AG = OFF_UG + (size_t)NB*NGRP*256;
static constexpr size_t OFF_GH = OFF_AG + (size_t)NB*NGRP*NH;
static constexpr size_t OFF_G2 = OFF_GH + (size_t)NB*NGRP*256;
static constexpr size_t WS_FLOATS = OFF_G2 + (size_t)NB*LL*GG;

typedef float f32x4 __attribute__((ext_vector_type(4)));
typedef short bf16x8 __attribute__((ext_vector_type(8)));

__device__ __forceinline__ float siluf(float v){ return v / (1.f + __expf(-v)); }
__device__ __forceinline__ float softplusf(float v){ return v > 20.f ? v : log1pf(__expf(v)); }

__device__ __forceinline__ unsigned short f2bf(float f){
    unsigned int u = __float_as_uint(f);
    u += 0x7fffu + ((u >> 16) & 1u);
    return (unsigned short)(u >> 16);
}
__device__ __forceinline__ float bf2f(unsigned short s){
    return __uint_as_float(((unsigned int)s) << 16);
}
__device__ __forceinline__ unsigned int pack2bf(float lo, float hi){
    return (unsigned int)f2bf(lo) | ((unsigned int)f2bf(hi) << 16);
}
__device__ __forceinline__ unsigned int packtr(float lo, float hi){
    return (__float_as_uint(hi) & 0xffff0000u) | (__float_as_uint(lo) >> 16);
}

__device__ __forceinline__ void load8(float* d, const float* p){
    float4 a = ((const float4*)p)[0];
    float4 b = ((const float4*)p)[1];
    d[0]=a.x; d[1]=a.y; d[2]=a.z; d[3]=a.w;
    d[4]=b.x; d[5]=b.y; d[6]=b.z; d[7]=b.w;
}

// K1a: tokenize x -> gt.
__global__ __launch_bounds__(64) void k1a_tok(
    const float* __restrict__ x, const float* __restrict__ tok_w,
    const float* __restrict__ tok_b, float* __restrict__ gtw)
{
    __shared__ float s_tok[GG*CF];
    int tid = threadIdx.x;
    int b  = blockIdx.x >> 6;
    int ck = blockIdx.x & 63;
    int l0 = (ck << 8) + (tid << 2);
    for (int i = tid; i < GG*CF; i += 64) s_tok[i] = tok_w[i];
    __syncthreads();
    float acc[4][GG];
    #pragma unroll
    for (int r = 0; r < 4; ++r)
        #pragma unroll
        for (int g = 0; g < GG; ++g) acc[r][g] = tok_b[g];
    const float* xb = x + (size_t)b*CF*LL + l0;
    #pragma unroll 8
    for (int c = 0; c < CF; ++c) {
        float4 xv = *(const float4*)(xb + (size_t)c*LL);
        float xa[4] = {xv.x, xv.y, xv.z, xv.w};
        #pragma unroll
        for (int g = 0; g < GG; ++g) {
            float w = s_tok[g*CF + c];
            #pragma unroll
            for (int r = 0; r < 4; ++r) acc[r][g] = fmaf(xa[r], w, acc[r][g]);
        }
    }
    float* gp = gtw + ((size_t)b*LL + l0)*GG;
    #pragma unroll
    for (int r = 0; r < 4; ++r) {
        ((float4*)gp)[r*2+0] = make_float4(acc[r][0],acc[r][1],acc[r][2],acc[r][3]);
        ((float4*)gp)[r*2+1] = make_float4(acc[r][4],acc[r][5],acc[r][6],acc[r][7]);
    }
}

// Shared W-build: combined conv+in_proj weight W[64][32] bf16, bias2, boundary corr.
__device__ __forceinline__ void build_W(
    int tid, const float* ipw, const float* ipb, const float* cw, const float* cb,
    unsigned short* Wt, float* s_bias, float* s_c0, float* s_c1, float* s_wdt)
{
    int col = tid & 63, kb = tid >> 6;
    unsigned int wd0=0u, wd1=0u, wd2=0u, wd3=0u;
    if (col < 48) {
        if (kb < 3) {
            float cwv = cw[col*3 + (2-kb)];
            const float* iprow = ipw + (16+col)*8;
            wd0 = pack2bf(iprow[0]*cwv, iprow[1]*cwv);
            wd1 = pack2bf(iprow[2]*cwv, iprow[3]*cwv);
            wd2 = pack2bf(iprow[4]*cwv, iprow[5]*cwv);
            wd3 = pack2bf(iprow[6]*cwv, iprow[7]*cwv);
        }
    } else if (kb == 0) {
        const float* iprow = ipw + (col-48)*8;
        wd0 = pack2bf(iprow[0], iprow[1]);
        wd1 = pack2bf(iprow[2], iprow[3]);
        wd2 = pack2bf(iprow[4], iprow[5]);
        wd3 = pack2bf(iprow[6], iprow[7]);
    }
    *(uint4*)&Wt[col*32 + kb*8] = make_uint4(wd0,wd1,wd2,wd3);
    if (kb == 0) {
        float bias;
        if (col < 48) {
            float w0 = cw[col*3], w1 = cw[col*3+1], w2 = cw[col*3+2];
            float ib = ipb[16+col];
            bias = cb[col] + ib*(w0+w1+w2);
            s_c0[col] = ib*(w0+w1);
            s_c1[col] = ib*w0;
        } else bias = ipb[col-48];
        s_bias[col] = bias;
    } else if (kb == 1 && col < 16) s_wdt[col] = ipw[512 + col];
}

// K2a: MFMA staging (x,B tiles) + cumsum + WX + chunk end-state MFMA -> U2, Ac.
__global__ __launch_bounds__(256) void k2a_state(
    const float* __restrict__ gtw,
    const float* __restrict__ ipw, const float* __restrict__ ipb,
    const float* __restrict__ cw, const float* __restrict__ cb,
    const float* __restrict__ A_log, const float* __restrict__ dt_bias,
    float* __restrict__ U2w, float* __restrict__ Acw)
{
    __shared__ __align__(16) unsigned short Wt[64*32];
    __shared__ float s_bias[64], s_c0[48], s_c1[48], s_wdt[16];
    __shared__ __align__(16) unsigned short XTbf[16*72];   // x^T; overwritten by WX
    __shared__ __align__(16) unsigned short BTbf[16*72];   // B^T
    __shared__ float s_dt[64][2], s_nda[64][2], s_w[64][2];

    int tid = threadIdx.x;
    int b = blockIdx.x >> 8, c = blockIdx.x & 255;
    build_W(tid, ipw, ipb, cw, cb, Wt, s_bias, s_c0, s_c1, s_wdt);
    __syncthreads();                                    // B0

    float a0e = __expf(A_log[0]), a1e = __expf(A_log[1]);
    float dtb0 = dt_bias[0], dtb1 = dt_bias[1];
    float bdt0 = ipb[64], bdt1 = ipb[65];

    int lane = tid & 63, wv = tid >> 6;
    int ar = lane & 15, kb = lane >> 4;
    int t4 = wv*16 + kb*4;

    // A operand from gt (rows shifted by kb), fp32 row kept for dt
    float fr[8];
    bf16x8 aop = {0,0,0,0,0,0,0,0};
    int rowi = c*CHN + wv*16 + ar - kb;
    if (kb < 3 && rowi >= 0) {
        load8(fr, gtw + ((size_t)b*LL + rowi)*GG);
        unsigned int* ap = (unsigned int*)&aop;
        ap[0] = pack2bf(fr[0],fr[1]); ap[1] = pack2bf(fr[2],fr[3]);
        ap[2] = pack2bf(fr[4],fr[5]); ap[3] = pack2bf(fr[6],fr[7]);
    }
    f32x4 st0, st1;
    {
        float bs0 = s_bias[ar], bs1 = s_bias[16+ar];
        f32x4 c0 = {bs0,bs0,bs0,bs0};
        f32x4 c1 = {bs1,bs1,bs1,bs1};
        bf16x8 bw0 = *(const bf16x8*)&Wt[ar*32 + kb*8];
        bf16x8 bw1 = *(const bf16x8*)&Wt[(16+ar)*32 + kb*8];
        st0 = __builtin_amdgcn_mfma_f32_16x16x32_bf16(aop, bw0, c0, 0, 0, 0);
        st1 = __builtin_amdgcn_mfma_f32_16x16x32_bf16(aop, bw1, c1, 0, 0, 0);
    }
    if (c == 0 && wv == 0 && kb == 0) {    // chunk-0 boundary bias fixup (rows 0,1)
        st0[0] -= s_c0[ar];    st0[1] -= s_c1[ar];
        st1[0] -= s_c0[16+ar]; st1[1] -= s_c1[16+ar];
    }
    if (kb == 0) {                          // dt for row wv*16+ar (fp32-exact)
        float d0 = bdt0, d1 = bdt1;
        #pragma unroll
        for (int g = 0; g < 8; ++g) {
            d0 = fmaf(fr[g], s_wdt[g],   d0);
            d1 = fmaf(fr[g], s_wdt[8+g], d1);
        }
        float dt0 = softplusf(d0 + dtb0), dt1 = softplusf(d1 + dtb1);
        int row = wv*16 + ar;
        s_dt[row][0] = dt0; s_dt[row][1] = dt1;
        s_nda[row][0] = -dt0*a0e; s_nda[row][1] = -dt1*a1e;
    }
    {   // silu + transposed b64 stores
        float v0 = siluf(st0[0]), v1 = siluf(st0[1]), v2 = siluf(st0[2]), v3 = siluf(st0[3]);
        *(uint2*)&XTbf[ar*72 + t4] = make_uint2(pack2bf(v0,v1), pack2bf(v2,v3));
        v0 = siluf(st1[0]); v1 = siluf(st1[1]); v2 = siluf(st1[2]); v3 = siluf(st1[3]);
        *(uint2*)&BTbf[ar*72 + t4] = make_uint2(pack2bf(v0,v1), pack2bf(v2,v3));
    }
    __syncthreads();                                    // B1

    if (tid < 64) {                                     // cumsum + weights + Ac
        int rr = tid;
        float v0 = s_nda[rr][0], v1 = s_nda[rr][1];
        #pragma unroll
        for (int off = 1; off < 64; off <<= 1) {
            float t0 = __shfl_up(v0, off);
            float t1 = __shfl_up(v1, off);
            if (rr >= off) { v0 += t0; v1 += t1; }
        }
        float f0 = __shfl(v0, 63), f1 = __shfl(v1, 63);
        s_w[rr][0] = __expf(f0 - v0) * s_dt[rr][0];
        s_w[rr][1] = __expf(f1 - v1) * s_dt[rr][1];
        if (rr == 63)
            *(float2*)(Acw + ((size_t)b*NCH + c)*2) = make_float2(__expf(f0), __expf(f1));
    }
    __syncthreads();                                    // B2

    if (tid < 128) {   // WX = w*x, in place over XTbf
        int p = tid >> 3, seg = tid & 7;
        int s0 = seg*8, he = p >> 3;
        unsigned short* xp = &XTbf[p*72 + s0];
        unsigned int wd[4];
        #pragma unroll
        for (int j = 0; j < 4; ++j) {
            float lo = bf2f(xp[2*j])   * s_w[s0+2*j][he];
            float hi = bf2f(xp[2*j+1]) * s_w[s0+2*j+1][he];
            wd[j] = pack2bf(lo, hi);
        }
        *(uint4*)xp = make_uint4(wd[0],wd[1],wd[2],wd[3]);
    }
    __syncthreads();                                    // B3

    if (tid < 64) {
        int ar2 = tid & 15, kb2 = tid >> 4;
        f32x4 acc = {0.f, 0.f, 0.f, 0.f};
        #pragma unroll
        for (int kk = 0; kk < 2; ++kk) {
            bf16x8 aw = *(const bf16x8*)&XTbf[ar2*72 + kk*32 + kb2*8];
            bf16x8 bb = *(const bf16x8*)&BTbf[ar2*72 + kk*32 + kb2*8];
            acc = __builtin_amdgcn_mfma_f32_16x16x32_bf16(aw, bb, acc, 0, 0, 0);
        }
        #pragma unroll
        for (int rg = 0; rg < 4; ++rg)
            U2w[(((size_t)b*NCH + c) << 8) + (kb2*4+rg)*16 + ar2] = acc[rg];
    }
}

// K4c1: scan 16 chunks within each group.
__global__ void k4c1(const float* __restrict__ U2w, const float* __restrict__ Acw,
                     float* __restrict__ phw, float* __restrict__ cpw,
                     float* __restrict__ Ugw, float* __restrict__ Agw)
{
    int b = blockIdx.x >> 4, grp = blockIdx.x & 15;
    int e = threadIdx.x, he = e >> 7;
    size_t base = (size_t)b*NCH + grp*16;
    float u[16], A[16];
    #pragma unroll
    for (int j = 0; j < 16; ++j) u[j] = U2w[((base + j) << 8) + e];
    #pragma unroll
    for (int j = 0; j < 16; ++j) A[j] = Acw[(base + j)*2 + he];
    float h = 0.f, cp = 1.f;
    #pragma unroll
    for (int j = 0; j < 16; ++j) {
        phw[((base + j) << 8) + e] = h;
        if ((e & 127) == 0) cpw[(base + j)*2 + he] = cp;
        h = fmaf(A[j], h, u[j]);
        cp *= A[j];
    }
    Ugw[(((size_t)b*NGRP + grp) << 8) + e] = h;
    if ((e & 127) == 0) Agw[((size_t)b*NGRP + grp)*2 + he] = cp;
}

// K4c2: scan 16 group summaries.
__global__ void k4c2(const float* __restrict__ Ugw, const float* __restrict__ Agw,
                     float* __restrict__ ghw)
{
    int b = blockIdx.x, e = threadIdx.x, he = e >> 7;
    float u[NGRP], ag[NGRP];
    #pragma unroll
    for (int g = 0; g < NGRP; ++g) {
        u[g]  = Ugw[(((size_t)b*NGRP + g) << 8) + e];
        ag[g] = Agw[((size_t)b*NGRP + g)*2 + he];
    }
    float h = 0.f;
    #pragma unroll
    for (int g = 0; g < NGRP; ++g) {
        ghw[(((size_t)b*NGRP + g) << 8) + e] = h;
        h = fmaf(ag[g], h, u[g]);
    }
}

// K2b: MFMA staging (x,B,C,z) + SSD + hin correction + epilogue -> g2.
__global__ __launch_bounds__(256) void k2b_fused(
    const float* __restrict__ gtw,
    const float* __restrict__ ipw, const float* __restrict__ ipb,
    const float* __restrict__ cw, const float* __restrict__ cb,
    const float* __restrict__ A_log, const float* __restrict__ dt_bias,
    const float* __restrict__ Dv, const float* __restrict__ norm_w,
    const float* __restrict__ out_w, const float* __restrict__ out_b,
    const float* __restrict__ phw, const float* __restrict__ cpw,
    const float* __restrict__ ghw,
    float* __restrict__ g2w)
{
    __shared__ __align__(16) unsigned short Wt[64*32];
    __shared__ float s_bias[64], s_c0[48], s_c1[48], s_wdt[16];
    __shared__ union { unsigned short Ct[64*40]; float yb[64*20]; } uC;
    __shared__ __align__(16) unsigned short Bt[64*40];
    __shared__ __align__(16) unsigned short XTbf[16*72];
    __shared__ float zf[64*17];
    __shared__ __align__(16) unsigned short M2[2][64*72];
    __shared__ __align__(16) unsigned short Cp0[64*16], Cp1[64*16];
    __shared__ __align__(16) unsigned short hinT[2][8*16];
    __shared__ float s_hin[256];
    __shared__ float s_dt[64][2], s_nda[64][2], s_la[64][2];
    __shared__ float s_eti[2][64], s_etd[2][64], s_esc[2][4][4];
    __shared__ float s_ow[128], s_nw[16], s_ob[8];

    int tid = threadIdx.x;
    int b = blockIdx.x >> 8, c = blockIdx.x & 255;
    build_W(tid, ipw, ipb, cw, cb, Wt, s_bias, s_c0, s_c1, s_wdt);
    {   // hin reconstruction
        int grp = c >> 4;
        float gh  = ghw[(((size_t)b*NGRP + grp) << 8) + tid];
        float cpv = cpw[((size_t)b*NCH + c)*2 + (tid >> 7)];
        float phv = phw[(((size_t)b*NCH + c) << 8) + tid];
        s_hin[tid] = fmaf(cpv, gh, phv);
    }
    // zero K-pad of Bt/Ct + small weights
    if (tid < 128) {
        *(uint4*)&Bt[(tid>>1)*40 + 16 + (tid&1)*8] = make_uint4(0,0,0,0);
        s_ow[tid] = out_w[tid];
    } else {
        int t2 = tid - 128;
        *(uint4*)&uC.Ct[(t2>>1)*40 + 16 + (t2&1)*8] = make_uint4(0,0,0,0);
        if (t2 < 16) s_nw[t2] = norm_w[t2];
        else if (t2 < 24) s_ob[t2-16] = out_b[t2-16];
    }
    __syncthreads();                                      // B0

    float a0e = __expf(A_log[0]), a1e = __expf(A_log[1]);
    float dtb0 = dt_bias[0], dtb1 = dt_bias[1];
    float bdt0 = ipb[64], bdt1 = ipb[65];
    float D0 = Dv[0], D1 = Dv[1];

    int lane = tid & 63, wv = tid >> 6;
    int ar = lane & 15, kb = lane >> 4;
    int trow = wv*16 + kb*4;

    // ---- MFMA staging: A from gt, 4 col-tiles (x, B, C, z) ----
    float fr[8];
    bf16x8 aop = {0,0,0,0,0,0,0,0};
    int rowi = c*CHN + wv*16 + ar - kb;
    if (kb < 3 && rowi >= 0) {
        load8(fr, gtw + ((size_t)b*LL + rowi)*GG);
        unsigned int* ap = (unsigned int*)&aop;
        ap[0] = pack2bf(fr[0],fr[1]); ap[1] = pack2bf(fr[2],fr[3]);
        ap[2] = pack2bf(fr[4],fr[5]); ap[3] = pack2bf(fr[6],fr[7]);
    }
    f32x4 st0, st1, st2, st3;
    {
        float b0 = s_bias[ar], b1 = s_bias[16+ar], b2 = s_bias[32+ar], b3 = s_bias[48+ar];
        f32x4 c0v = {b0,b0,b0,b0}, c1v = {b1,b1,b1,b1};
        f32x4 c2v = {b2,b2,b2,b2}, c3v = {b3,b3,b3,b3};
        st0 = __builtin_amdgcn_mfma_f32_16x16x32_bf16(aop, *(const bf16x8*)&Wt[ar*32 + kb*8],       c0v, 0,0,0);
        st1 = __builtin_amdgcn_mfma_f32_16x16x32_bf16(aop, *(const bf16x8*)&Wt[(16+ar)*32 + kb*8],  c1v, 0,0,0);
        st2 = __builtin_amdgcn_mfma_f32_16x16x32_bf16(aop, *(const bf16x8*)&Wt[(32+ar)*32 + kb*8],  c2v, 0,0,0);
        st3 = __builtin_amdgcn_mfma_f32_16x16x32_bf16(aop, *(const bf16x8*)&Wt[(48+ar)*32 + kb*8],  c3v, 0,0,0);
    }
    if (c == 0 && wv == 0 && kb == 0) {
        st0[0] -= s_c0[ar];    st0[1] -= s_c1[ar];
        st1[0] -= s_c0[16+ar]; st1[1] -= s_c1[16+ar];
        st2[0] -= s_c0[32+ar]; st2[1] -= s_c1[32+ar];
    }
    if (kb == 0) {                          // dt (fp32-exact)
        float d0 = bdt0, d1 = bdt1;
        #pragma unroll
        for (int g = 0; g < 8; ++g) {
            d0 = fmaf(fr[g], s_wdt[g],   d0);
            d1 = fmaf(fr[g], s_wdt[8+g], d1);
        }
        float dt0 = softplusf(d0 + dtb0), dt1 = softplusf(d1 + dtb1);
        int row = wv*16 + ar;
        s_dt[row][0] = dt0; s_dt[row][1] = dt1;
        s_nda[row][0] = -dt0*a0e; s_nda[row][1] = -dt1*a1e;
    }
    {   // x -> XT (b64); B,C -> row tiles via shfl-pair dwords; z raw -> zf
        float v0 = siluf(st0[0]), v1 = siluf(st0[1]), v2 = siluf(st0[2]), v3 = siluf(st0[3]);
        *(uint2*)&XTbf[ar*72 + trow] = make_uint2(pack2bf(v0,v1), pack2bf(v2,v3));
        #pragma unroll
        for (int rg = 0; rg < 4; ++rg) {
            float vB = siluf(st1[rg]);
            float vC = siluf(st2[rg]);
            float pB = __shfl_xor(vB, 1);
            float pC = __shfl_xor(vC, 1);
            if (!(ar & 1)) {
                *(unsigned int*)&Bt[(trow+rg)*40 + ar]    = pack2bf(vB, pB);
                *(unsigned int*)&uC.Ct[(trow+rg)*40 + ar] = pack2bf(vC, pC);
            }
            zf[(trow+rg)*17 + ar] = st3[rg];
        }
    }
    float g0[8];
    if ((tid & 3) == 0)    // residual row preload (hidden under later phases)
        load8(g0, gtw + ((size_t)b*LL + c*CHN + (tid>>2))*GG);
    __syncthreads();                                      // B1

    // ---- G-MFMAs (causal tiles) || wave-0 cumsum ----
    f32x4 gT[4];
    {
        bf16x8 aC = *(const bf16x8*)&uC.Ct[(wv*16 + ar)*40 + kb*8];
        #pragma unroll
        for (int ss = 0; ss < 4; ++ss) {
            f32x4 g = {0.f, 0.f, 0.f, 0.f};
            if (ss <= wv) {
                bf16x8 bB = *(const bf16x8*)&Bt[(ss*16 + ar)*40 + kb*8];
                g = __builtin_amdgcn_mfma_f32_16x16x32_bf16(aC, bB, g, 0, 0, 0);
            }
            gT[ss] = g;
        }
    }
    if (tid < 64) {
        int rr = tid;
        float v0 = s_nda[rr][0], v1 = s_nda[rr][1];
        #pragma unroll
        for (int off = 1; off < 64; off <<= 1) {
            float t0 = __shfl_up(v0, off);
            float t1 = __shfl_up(v1, off);
            if (rr >= off) { v0 += t0; v1 += t1; }
        }
        s_la[rr][0] = v0; s_la[rr][1] = v1;
    }
    __syncthreads();                                      // B2

    // ---- Cp + hinT (tid<128) || exp tables (tid>=128) ----
    if (tid < 128) {
        int h = tid >> 6;
        int rr = tid & 63;
        float sc = __expf(s_la[rr][h]);
        unsigned short* Cp = h ? Cp1 : Cp0;
        unsigned int* dst = (unsigned int*)&Cp[rr*16];
        #pragma unroll
        for (int j = 0; j < 8; ++j)
            dst[j] = pack2bf(sc * bf2f(uC.Ct[rr*40 + j*2]),
                             sc * bf2f(uC.Ct[rr*40 + j*2 + 1]));
        if (tid < 32) {
            int i = tid;
            int hh = i >> 4, p = (i >> 1) & 7, half = i & 1;
            unsigned int wd[4];
            #pragma unroll
            for (int j = 0; j < 4; ++j)
                wd[j] = pack2bf(s_hin[hh*128 + p*16 + half*8 + 2*j],
                                s_hin[hh*128 + p*16 + half*8 + 2*j + 1]);
            *(uint4*)&hinT[hh][p*16 + half*8] = make_uint4(wd[0],wd[1],wd[2],wd[3]);
        }
    } else {
        int i = tid - 128;
        int h = i >> 6, s = i & 63;
        int anc = s & ~15;
        float d = s_la[anc][h] - s_la[s][h];
        s_eti[h][s] = __expf(-d);
        s_etd[h][s] = __expf(d) * s_dt[s][h];
        if (i < 32) {
            int h2 = i >> 4, wt = (i >> 2) & 3, ws = i & 3;
            s_esc[h2][wt][ws] = (wt >= ws) ?
                __expf(s_la[wt*16][h2] - s_la[ws*16][h2]) : 0.f;
        }
    }
    __syncthreads();                                      // B3

    {   // ---- M~ both heads (table-driven, trunc-pack dword stores) ----
        float rowf0[4], rowf1[4];
        #pragma unroll
        for (int rg = 0; rg < 4; ++rg) {
            rowf0[rg] = s_eti[0][trow+rg];
            rowf1[rg] = s_eti[1][trow+rg];
        }
        #pragma unroll
        for (int ss = 0; ss < 4; ++ss) {
            int s = ss*16 + ar;
            if (ss > wv) {
                if (!(ar & 1)) {
                    #pragma unroll
                    for (int rg = 0; rg < 4; ++rg) {
                        *(unsigned int*)&M2[0][(trow+rg)*72 + ss*16 + ar] = 0u;
                        *(unsigned int*)&M2[1][(trow+rg)*72 + ss*16 + ar] = 0u;
                    }
                }
                continue;
            }
            float colf0 = s_esc[0][wv][ss] * s_etd[0][s];
            float colf1 = s_esc[1][wv][ss] * s_etd[1][s];
            #pragma unroll
            for (int rg = 0; rg < 4; ++rg) {
                bool keep = (s <= trow+rg);
                float m0 = keep ? rowf0[rg]*colf0*gT[ss][rg] : 0.f;
                float m1 = keep ? rowf1[rg]*colf1*gT[ss][rg] : 0.f;
                float m0p = __shfl_xor(m0, 1);
                float m1p = __shfl_xor(m1, 1);
                if (!(ar & 1)) {
                    *(unsigned int*)&M2[0][(trow+rg)*72 + ss*16 + ar] = packtr(m0, m0p);
                    *(unsigned int*)&M2[1][(trow+rg)*72 + ss*16 + ar] = packtr(m1, m1p);
                }
            }
        }
    }
    __syncthreads();                                      // B4

    {   // ---- Y = M~.X + Cp.hinT, both heads; yb store (overlays Ct) ----
        int p = ar;
        f32x4 acc0 = {0.f,0.f,0.f,0.f}, acc1 = {0.f,0.f,0.f,0.f};
        #pragma unroll
        for (int kk = 0; kk < 2; ++kk) {
            bf16x8 am0 = *(const bf16x8*)&M2[0][(wv*16 + ar)*72 + kk*32 + kb*8];
            bf16x8 am1 = *(const bf16x8*)&M2[1][(wv*16 + ar)*72 + kk*32 + kb*8];
            bf16x8 bx0 = {0,0,0,0,0,0,0,0}, bx1 = {0,0,0,0,0,0,0,0};
            if (p < 8) {
                bx0 = *(const bf16x8*)&XTbf[p*72 + kk*32 + kb*8];
                bx1 = *(const bf16x8*)&XTbf[(8+p)*72 + kk*32 + kb*8];
            }
            acc0 = __builtin_amdgcn_mfma_f32_16x16x32_bf16(am0, bx0, acc0, 0, 0, 0);
            acc1 = __builtin_amdgcn_mfma_f32_16x16x32_bf16(am1, bx1, acc1, 0, 0, 0);
        }
        bf16x8 aCp0 = {0,0,0,0,0,0,0,0}, aCp1 = {0,0,0,0,0,0,0,0};
        bf16x8 bh0 = {0,0,0,0,0,0,0,0}, bh1 = {0,0,0,0,0,0,0,0};
        if (kb < 2) {
            aCp0 = *(const bf16x8*)&Cp0[(wv*16 + ar)*16 + kb*8];
            aCp1 = *(const bf16x8*)&Cp1[(wv*16 + ar)*16 + kb*8];
            if (ar < 8) {
                bh0 = *(const bf16x8*)&hinT[0][ar*16 + kb*8];
                bh1 = *(const bf16x8*)&hinT[1][ar*16 + kb*8];
            }
        }
        acc0 = __builtin_amdgcn_mfma_f32_16x16x32_bf16(aCp0, bh0, acc0, 0, 0, 0);
        acc1 = __builtin_amdgcn_mfma_f32_16x16x32_bf16(aCp1, bh1, acc1, 0, 0, 0);
        if (p < 8) {
            #pragma unroll
            for (int rg = 0; rg < 4; ++rg) {
                int t = trow + rg;
                uC.yb[t*20 + p]     = fmaf(D0, bf2f(XTbf[p*72 + t]),     acc0[rg]);
                uC.yb[t*20 + 8 + p] = fmaf(D1, bf2f(XTbf[(8+p)*72 + t]), acc1[rg]);
            }
        }
    }
    __syncthreads();                                      // B5

    {   // ---- epilogue: silu(z) gate, RMSNorm, out proj, residual ----
        int r = tid >> 2, q = tid & 3;
        float vv[4]; float ssq = 0.f;
        #pragma unroll
        for (int j = 0; j < 4; ++j) {
            int hp = q*4 + j;
            float zz = zf[r*17 + hp];
            float y = uC.yb[r*20 + hp];
            float w = y * siluf(zz);
            vv[j] = w; ssq = fmaf(w, w, ssq);
        }
        ssq += __shfl_xor(ssq, 1);
        ssq += __shfl_xor(ssq, 2);
        float rn = rsqrtf(ssq*(1.f/16.f) + 1e-5f);
        float o[8];
        #pragma unroll
        for (int g = 0; g < 8; ++g) o[g] = 0.f;
        #pragma unroll
        for (int j = 0; j < 4; ++j) {
            float wj = vv[j] * rn * s_nw[q*4+j];
            #pragma unroll
            for (int g = 0; g < 8; ++g) o[g] = fmaf(wj, s_ow[g*16 + q*4 + j], o[g]);
        }
        #pragma unroll
        for (int g = 0; g < 8; ++g) {
            o[g] += __shfl_xor(o[g], 1);
            o[g] += __shfl_xor(o[g], 2);
        }
        if (q == 0) {
            #pragma unroll
            for (int g = 0; g < 8; ++g) o[g] += s_ob[g] + g0[g];
            float* gp = g2w + ((size_t)b*LL + c*CHN + r)*GG;
            ((float4*)gp)[0] = make_float4(o[0],o[1],o[2],o[3]);
            ((float4*)gp)[1] = make_float4(o[4],o[5],o[6],o[7]);
        }
    }
}

// K5b: out = x + detok(g2) + detok_b.
__global__ __launch_bounds__(64) void k5b_detok(
    const float* __restrict__ x, const float* __restrict__ g2w,
    const float* __restrict__ dkw, const float* __restrict__ dkb,
    float* __restrict__ outp)
{
    __shared__ float s_dw[CF*GG];
    __shared__ float s_db[CF];
    int tid = threadIdx.x;
    int b  = blockIdx.x >> 6;
    int ck = blockIdx.x & 63;
    int l0 = (ck << 8) + (tid << 2);
    for (int i = tid; i < CF*GG; i += 64) s_dw[i] = dkw[i];
    s_db[tid] = dkb[tid];
    __syncthreads();
    float g2v[4][8];
    const float* gp = g2w + ((size_t)b*LL + l0)*GG;
    #pragma unroll
    for (int r = 0; r < 4; ++r) load8(g2v[r], gp + r*GG);
    const float* xb = x + (size_t)b*CF*LL + l0;
    float* ob = outp + (size_t)b*CF*LL + l0;
    #pragma unroll 4
    for (int c = 0; c < CF; ++c) {
        float4 xv = *(const float4*)(xb + (size_t)c*LL);
        float bias = s_db[c];
        float oa[4] = {xv.x+bias, xv.y+bias, xv.z+bias, xv.w+bias};
        #pragma unroll
        for (int g = 0; g < GG; ++g) {
            float w = s_dw[c*GG+g];
            #pragma unroll
            for (int r = 0; r < 4; ++r) oa[r] = fmaf(g2v[r][g], w, oa[r]);
        }
        *(float4*)(ob + (size_t)c*LL) = make_float4(oa[0],oa[1],oa[2],oa[3]);
    }
}

extern "C" void kernel_launch(void* const* d_in, const int* in_sizes, int n_in,
                              void* d_out, int out_size, void* d_ws, size_t ws_size,
                              hipStream_t stream) {
    const float* x       = (const float*)d_in[0];
    const float* tok_w   = (const float*)d_in[1];
    const float* tok_b   = (const float*)d_in[2];
    const float* detok_w = (const float*)d_in[3];
    const float* detok_b = (const float*)d_in[4];
    const float* ipw     = (const float*)d_in[5];
    const float* ipb     = (const float*)d_in[6];
    const float* cw      = (const float*)d_in[7];
    const float* cb      = (const float*)d_in[8];
    const float* A_log   = (const float*)d_in[9];
    const float* Dv      = (const float*)d_in[10];
    const float* dt_bias = (const float*)d_in[11];
    const float* norm_w  = (const float*)d_in[12];
    const float* out_w   = (const float*)d_in[13];
    const float* out_b   = (const float*)d_in[14];
    float* ws = (float*)d_ws;
    float* outp = (float*)d_out;

    if (ws_size < WS_FLOATS * sizeof(float)) return;

    k1a_tok<<<NB*64, 64, 0, stream>>>(x, tok_w, tok_b, ws+OFF_GT);
    k2a_state<<<NB*NCH, 256, 0, stream>>>(ws+OFF_GT, ipw, ipb, cw, cb,
        A_log, dt_bias, ws+OFF_U2, ws+OFF_AC);
    k4c1<<<NB*NGRP, 256, 0, stream>>>(ws+OFF_U2, ws+OFF_AC,
        ws+OFF_PH, ws+OFF_CP, ws+OFF_UG, ws+OFF_AG);
    k4c2<<<NB, 256, 0, stream>>>(ws+OFF_UG, ws+OFF_AG, ws+OFF_GH);
    k2b_fused<<<NB*NCH, 256, 0, stream>>>(ws+OFF_GT, ipw, ipb, cw, cb,
        A_log, dt_bias, Dv, norm_w, out_w, out_b,
        ws+OFF_PH, ws+OFF_CP, ws+OFF_GH, ws+OFF_G2);
    k5b_detok<<<NB*64, 64, 0, stream>>>(x, ws+OFF_G2, detok_w, detok_b, outp);
}

// Round 12
// 122.194 us; speedup vs baseline: 1.0999x; 1.0999x over previous
//
#include <hip/hip_runtime.h>
#include <math.h>

#define NB 16
#define CF 64
#define LL 16384
#define GG 8
#define NH 2
#define CHN 64
#define NCH 256
#define NGRP 16

static constexpr size_t OFF_GT = 0;
static constexpr size_t OFF_U2 = OFF_GT + (size_t)NB*LL*GG;
static constexpr size_t OFF_AC = OFF_U2 + (size_t)NB*NCH*256;
static constexpr size_t OFF_PH = OFF_AC + (size_t)NB*NCH*NH;
static constexpr size_t OFF_CP = OFF_PH + (size_t)NB*NCH*256;
static constexpr size_t OFF_UG = OFF_CP + (size_t)NB*NCH*NH;
static constexpr size_t OFF_AG = OFF_UG + (size_t)NB*NGRP*256;
static constexpr size_t OFF_GH = OFF_AG + (size_t)NB*NGRP*NH;
static constexpr size_t OFF_G2 = OFF_GH + (size_t)NB*NGRP*256;
static constexpr size_t OFF_ST = OFF_G2 + (size_t)NB*LL*GG;
// per-chunk staged record: 1792 floats = XT[512] B[512] C[512] la[128] dt[128]
static constexpr size_t WS_FLOATS = OFF_ST + (size_t)NB*NCH*1792;

typedef float f32x4 __attribute__((ext_vector_type(4)));
typedef short bf16x8 __attribute__((ext_vector_type(8)));

__device__ __forceinline__ float siluf(float v){ return v / (1.f + __expf(-v)); }
__device__ __forceinline__ float softplusf(float v){ return v > 20.f ? v : log1pf(__expf(v)); }

__device__ __forceinline__ unsigned short f2bf(float f){
    unsigned int u = __float_as_uint(f);
    u += 0x7fffu + ((u >> 16) & 1u);
    return (unsigned short)(u >> 16);
}
__device__ __forceinline__ float bf2f(unsigned short s){
    return __uint_as_float(((unsigned int)s) << 16);
}
__device__ __forceinline__ unsigned int pack2bf(float lo, float hi){
    return (unsigned int)f2bf(lo) | ((unsigned int)f2bf(hi) << 16);
}
__device__ __forceinline__ unsigned int packtr(float lo, float hi){
    return (__float_as_uint(hi) & 0xffff0000u) | (__float_as_uint(lo) >> 16);
}

__device__ __forceinline__ void load8(float* d, const float* p){
    float4 a = ((const float4*)p)[0];
    float4 b = ((const float4*)p)[1];
    d[0]=a.x; d[1]=a.y; d[2]=a.z; d[3]=a.w;
    d[4]=b.x; d[5]=b.y; d[6]=b.z; d[7]=b.w;
}

// K1a: tokenize x -> gt.
__global__ __launch_bounds__(64) void k1a_tok(
    const float* __restrict__ x, const float* __restrict__ tok_w,
    const float* __restrict__ tok_b, float* __restrict__ gtw)
{
    __shared__ float s_tok[GG*CF];
    int tid = threadIdx.x;
    int b  = blockIdx.x >> 6;
    int ck = blockIdx.x & 63;
    int l0 = (ck << 8) + (tid << 2);
    for (int i = tid; i < GG*CF; i += 64) s_tok[i] = tok_w[i];
    __syncthreads();
    float acc[4][GG];
    #pragma unroll
    for (int r = 0; r < 4; ++r)
        #pragma unroll
        for (int g = 0; g < GG; ++g) acc[r][g] = tok_b[g];
    const float* xb = x + (size_t)b*CF*LL + l0;
    #pragma unroll 8
    for (int c = 0; c < CF; ++c) {
        float4 xv = *(const float4*)(xb + (size_t)c*LL);
        float xa[4] = {xv.x, xv.y, xv.z, xv.w};
        #pragma unroll
        for (int g = 0; g < GG; ++g) {
            float w = s_tok[g*CF + c];
            #pragma unroll
            for (int r = 0; r < 4; ++r) acc[r][g] = fmaf(xa[r], w, acc[r][g]);
        }
    }
    float* gp = gtw + ((size_t)b*LL + l0)*GG;
    #pragma unroll
    for (int r = 0; r < 4; ++r) {
        ((float4*)gp)[r*2+0] = make_float4(acc[r][0],acc[r][1],acc[r][2],acc[r][3]);
        ((float4*)gp)[r*2+1] = make_float4(acc[r][4],acc[r][5],acc[r][6],acc[r][7]);
    }
}

// Shared W-build: combined conv+in_proj weight W[64][32] bf16, bias2, boundary corr.
__device__ __forceinline__ void build_W(
    int tid, const float* ipw, const float* ipb, const float* cw, const float* cb,
    unsigned short* Wt, float* s_bias, float* s_c0, float* s_c1, float* s_wdt)
{
    int col = tid & 63, kb = tid >> 6;
    unsigned int wd0=0u, wd1=0u, wd2=0u, wd3=0u;
    if (col < 48) {
        if (kb < 3) {
            float cwv = cw[col*3 + (2-kb)];
            const float* iprow = ipw + (16+col)*8;
            wd0 = pack2bf(iprow[0]*cwv, iprow[1]*cwv);
            wd1 = pack2bf(iprow[2]*cwv, iprow[3]*cwv);
            wd2 = pack2bf(iprow[4]*cwv, iprow[5]*cwv);
            wd3 = pack2bf(iprow[6]*cwv, iprow[7]*cwv);
        }
    } else if (kb == 0) {
        const float* iprow = ipw + (col-48)*8;
        wd0 = pack2bf(iprow[0], iprow[1]);
        wd1 = pack2bf(iprow[2], iprow[3]);
        wd2 = pack2bf(iprow[4], iprow[5]);
        wd3 = pack2bf(iprow[6], iprow[7]);
    }
    *(uint4*)&Wt[col*32 + kb*8] = make_uint4(wd0,wd1,wd2,wd3);
    if (kb == 0) {
        float bias;
        if (col < 48) {
            float w0 = cw[col*3], w1 = cw[col*3+1], w2 = cw[col*3+2];
            float ib = ipb[16+col];
            bias = cb[col] + ib*(w0+w1+w2);
            s_c0[col] = ib*(w0+w1);
            s_c1[col] = ib*w0;
        } else bias = ipb[col-48];
        s_bias[col] = bias;
    } else if (kb == 1 && col < 16) s_wdt[col] = ipw[512 + col];
}

// K2a: MFMA staging -> persist XT/Brow/Crow/la/dt; cumsum; WX; state MFMA -> U2, Ac.
__global__ __launch_bounds__(256) void k2a_state(
    const float* __restrict__ gtw,
    const float* __restrict__ ipw, const float* __restrict__ ipb,
    const float* __restrict__ cw, const float* __restrict__ cb,
    const float* __restrict__ A_log, const float* __restrict__ dt_bias,
    float* __restrict__ stw,
    float* __restrict__ U2w, float* __restrict__ Acw)
{
    __shared__ __align__(16) unsigned short Wt[64*32];
    __shared__ float s_bias[64], s_c0[48], s_c1[48], s_wdt[16];
    __shared__ __align__(16) unsigned short XTbf[16*72];   // x^T [p][s]
    __shared__ __align__(16) unsigned short BTbf[16*72];   // B^T [n][s]
    __shared__ __align__(16) unsigned short WXbf[16*72];   // (w*x)^T
    __shared__ __align__(16) unsigned short Brow[64*16];   // B row-major
    __shared__ __align__(16) unsigned short Crow[64*16];   // C row-major
    __shared__ float s_dt[64][2], s_nda[64][2], s_w[64][2];

    int tid = threadIdx.x;
    int b = blockIdx.x >> 8, c = blockIdx.x & 255;
    float* stp = stw + ((size_t)(b*NCH + c))*1792;
    build_W(tid, ipw, ipb, cw, cb, Wt, s_bias, s_c0, s_c1, s_wdt);
    __syncthreads();                                    // B0

    float a0e = __expf(A_log[0]), a1e = __expf(A_log[1]);
    float dtb0 = dt_bias[0], dtb1 = dt_bias[1];
    float bdt0 = ipb[64], bdt1 = ipb[65];

    int lane = tid & 63, wv = tid >> 6;
    int ar = lane & 15, kb = lane >> 4;
    int trow = wv*16 + kb*4;

    // staging MFMA: A from gt (rows shifted by kb); x, B, C column tiles
    float fr[8];
    bf16x8 aop = {0,0,0,0,0,0,0,0};
    int rowi = c*CHN + wv*16 + ar - kb;
    if (kb < 3 && rowi >= 0) {
        load8(fr, gtw + ((size_t)b*LL + rowi)*GG);
        unsigned int* ap = (unsigned int*)&aop;
        ap[0] = pack2bf(fr[0],fr[1]); ap[1] = pack2bf(fr[2],fr[3]);
        ap[2] = pack2bf(fr[4],fr[5]); ap[3] = pack2bf(fr[6],fr[7]);
    }
    f32x4 st0, st1, st2;
    {
        float b0 = s_bias[ar], b1 = s_bias[16+ar], b2 = s_bias[32+ar];
        f32x4 c0v = {b0,b0,b0,b0}, c1v = {b1,b1,b1,b1}, c2v = {b2,b2,b2,b2};
        st0 = __builtin_amdgcn_mfma_f32_16x16x32_bf16(aop, *(const bf16x8*)&Wt[ar*32 + kb*8],      c0v, 0,0,0);
        st1 = __builtin_amdgcn_mfma_f32_16x16x32_bf16(aop, *(const bf16x8*)&Wt[(16+ar)*32 + kb*8], c1v, 0,0,0);
        st2 = __builtin_amdgcn_mfma_f32_16x16x32_bf16(aop, *(const bf16x8*)&Wt[(32+ar)*32 + kb*8], c2v, 0,0,0);
    }
    if (c == 0 && wv == 0 && kb == 0) {    // chunk-0 boundary fixup (rows 0,1)
        st0[0] -= s_c0[ar];    st0[1] -= s_c1[ar];
        st1[0] -= s_c0[16+ar]; st1[1] -= s_c1[16+ar];
        st2[0] -= s_c0[32+ar]; st2[1] -= s_c1[32+ar];
    }
    if (kb == 0) {                          // dt for row wv*16+ar (fp32-exact)
        float d0 = bdt0, d1 = bdt1;
        #pragma unroll
        for (int g = 0; g < 8; ++g) {
            d0 = fmaf(fr[g], s_wdt[g],   d0);
            d1 = fmaf(fr[g], s_wdt[8+g], d1);
        }
        float dt0 = softplusf(d0 + dtb0), dt1 = softplusf(d1 + dtb1);
        int row = wv*16 + ar;
        s_dt[row][0] = dt0; s_dt[row][1] = dt1;
        s_nda[row][0] = -dt0*a0e; s_nda[row][1] = -dt1*a1e;
    }
    {   // x -> XT (b64); B -> BT (b64); B,C -> row tiles via shfl-pair dwords
        float v0 = siluf(st0[0]), v1 = siluf(st0[1]), v2 = siluf(st0[2]), v3 = siluf(st0[3]);
        *(uint2*)&XTbf[ar*72 + trow] = make_uint2(pack2bf(v0,v1), pack2bf(v2,v3));
        float b0 = siluf(st1[0]), b1 = siluf(st1[1]), b2 = siluf(st1[2]), b3 = siluf(st1[3]);
        *(uint2*)&BTbf[ar*72 + trow] = make_uint2(pack2bf(b0,b1), pack2bf(b2,b3));
        float bb[4] = {b0,b1,b2,b3};
        #pragma unroll
        for (int rg = 0; rg < 4; ++rg) {
            float vB = bb[rg];
            float vC = siluf(st2[rg]);
            float pB = __shfl_xor(vB, 1);
            float pC = __shfl_xor(vC, 1);
            if (!(ar & 1)) {
                *(unsigned int*)&Brow[(trow+rg)*16 + ar] = pack2bf(vB, pB);
                *(unsigned int*)&Crow[(trow+rg)*16 + ar] = pack2bf(vC, pC);
            }
        }
    }
    __syncthreads();                                    // B1

    if (tid < 64) {   // cumsum + weights + la/dt persist + Ac
        int rr = tid;
        float v0 = s_nda[rr][0], v1 = s_nda[rr][1];
        #pragma unroll
        for (int off = 1; off < 64; off <<= 1) {
            float t0 = __shfl_up(v0, off);
            float t1 = __shfl_up(v1, off);
            if (rr >= off) { v0 += t0; v1 += t1; }
        }
        float f0 = __shfl(v0, 63), f1 = __shfl(v1, 63);
        s_w[rr][0] = __expf(f0 - v0) * s_dt[rr][0];
        s_w[rr][1] = __expf(f1 - v1) * s_dt[rr][1];
        stp[1536 + rr*2 + 0] = v0;
        stp[1536 + rr*2 + 1] = v1;
        stp[1664 + rr*2 + 0] = s_dt[rr][0];
        stp[1664 + rr*2 + 1] = s_dt[rr][1];
        if (rr == 63)
            *(float2*)(Acw + ((size_t)b*NCH + c)*2) = make_float2(__expf(f0), __expf(f1));
    }
    __syncthreads();                                    // B2

    {   // WX build (tid<128) || XT persist (tid>=128); then Brow/Crow persist
        unsigned int* stX = (unsigned int*)stp;
        unsigned int* stB = (unsigned int*)(stp + 512);
        unsigned int* stC = (unsigned int*)(stp + 1024);
        if (tid < 128) {
            int p = tid >> 3, seg = tid & 7;
            int s0 = seg*8, he = p >> 3;
            const unsigned short* xp = &XTbf[p*72 + s0];
            unsigned int wd[4];
            #pragma unroll
            for (int j = 0; j < 4; ++j) {
                float lo = bf2f(xp[2*j])   * s_w[s0+2*j][he];
                float hi = bf2f(xp[2*j+1]) * s_w[s0+2*j+1][he];
                wd[j] = pack2bf(lo, hi);
            }
            *(uint4*)&WXbf[p*72 + s0] = make_uint4(wd[0],wd[1],wd[2],wd[3]);
            int row = tid >> 1, hf = tid & 1;
            *(uint4*)&stB[row*8 + hf*4] = *(const uint4*)&Brow[row*16 + hf*8];
        } else {
            int i = tid - 128;
            int p = i >> 3, seg = i & 7;
            *(uint4*)&stX[p*32 + seg*4] = *(const uint4*)&XTbf[p*72 + seg*8];
            int row = i >> 1, hf = i & 1;
            *(uint4*)&stC[row*8 + hf*4] = *(const uint4*)&Crow[row*16 + hf*8];
        }
    }
    __syncthreads();                                    // B3

    if (tid < 64) {
        int ar2 = tid & 15, kb2 = tid >> 4;
        f32x4 acc = {0.f, 0.f, 0.f, 0.f};
        #pragma unroll
        for (int kk = 0; kk < 2; ++kk) {
            bf16x8 aw = *(const bf16x8*)&WXbf[ar2*72 + kk*32 + kb2*8];
            bf16x8 bb = *(const bf16x8*)&BTbf[ar2*72 + kk*32 + kb2*8];
            acc = __builtin_amdgcn_mfma_f32_16x16x32_bf16(aw, bb, acc, 0, 0, 0);
        }
        #pragma unroll
        for (int rg = 0; rg < 4; ++rg)
            U2w[(((size_t)b*NCH + c) << 8) + (kb2*4+rg)*16 + ar2] = acc[rg];
    }
}

// K4c1: scan 16 chunks within each group.
__global__ void k4c1(const float* __restrict__ U2w, const float* __restrict__ Acw,
                     float* __restrict__ phw, float* __restrict__ cpw,
                     float* __restrict__ Ugw, float* __restrict__ Agw)
{
    int b = blockIdx.x >> 4, grp = blockIdx.x & 15;
    int e = threadIdx.x, he = e >> 7;
    size_t base = (size_t)b*NCH + grp*16;
    float u[16], A[16];
    #pragma unroll
    for (int j = 0; j < 16; ++j) u[j] = U2w[((base + j) << 8) + e];
    #pragma unroll
    for (int j = 0; j < 16; ++j) A[j] = Acw[(base + j)*2 + he];
    float h = 0.f, cp = 1.f;
    #pragma unroll
    for (int j = 0; j < 16; ++j) {
        phw[((base + j) << 8) + e] = h;
        if ((e & 127) == 0) cpw[(base + j)*2 + he] = cp;
        h = fmaf(A[j], h, u[j]);
        cp *= A[j];
    }
    Ugw[(((size_t)b*NGRP + grp) << 8) + e] = h;
    if ((e & 127) == 0) Agw[((size_t)b*NGRP + grp)*2 + he] = cp;
}

// K4c2: scan 16 group summaries.
__global__ void k4c2(const float* __restrict__ Ugw, const float* __restrict__ Agw,
                     float* __restrict__ ghw)
{
    int b = blockIdx.x, e = threadIdx.x, he = e >> 7;
    float u[NGRP], ag[NGRP];
    #pragma unroll
    for (int g = 0; g < NGRP; ++g) {
        u[g]  = Ugw[(((size_t)b*NGRP + g) << 8) + e];
        ag[g] = Agw[((size_t)b*NGRP + g)*2 + he];
    }
    float h = 0.f;
    #pragma unroll
    for (int g = 0; g < NGRP; ++g) {
        ghw[(((size_t)b*NGRP + g) << 8) + e] = h;
        h = fmaf(ag[g], h, u[g]);
    }
}

// K2b: consume staged tiles -> G, M~ (both heads), Y + hin correction, epilogue -> g2.
__global__ __launch_bounds__(256) void k2b_fused(
    const float* __restrict__ gtw,
    const float* __restrict__ ipw, const float* __restrict__ ipb,
    const float* __restrict__ Dv, const float* __restrict__ norm_w,
    const float* __restrict__ out_w, const float* __restrict__ out_b,
    const float* __restrict__ phw, const float* __restrict__ cpw,
    const float* __restrict__ ghw, const float* __restrict__ stw,
    float* __restrict__ g2w)
{
    __shared__ union {
        unsigned short Ct[64*40];     // C tile, K-pad zeroed
        float yb[64*20];              // y bounce (phase 3+)
    } uC;
    __shared__ __align__(16) unsigned short Bt[64*40];
    __shared__ __align__(16) unsigned short XTbf[16*72];
    __shared__ __align__(16) unsigned short M2[2][64*72];
    __shared__ __align__(16) unsigned short Cp0[64*16], Cp1[64*16];
    __shared__ __align__(16) unsigned short hinT[2][8*16];
    __shared__ float s_hin[256];
    __shared__ float s_la[128];
    __shared__ float s_eti[2][64], s_etd[2][64], s_esc[2][4][4];
    __shared__ float s_zw[128], s_ow[128], s_zb[16], s_nw[16], s_ob[8];

    int tid = threadIdx.x;
    int b = blockIdx.x >> 8, c = blockIdx.x & 255;
    const float* stp = stw + ((size_t)(b*NCH + c))*1792;
    const unsigned int* stX = (const unsigned int*)stp;
    const unsigned int* stB = (const unsigned int*)(stp + 512);
    const unsigned int* stC = (const unsigned int*)(stp + 1024);

    int r = tid >> 2, sub = tid & 3;
    float g0[8];
    load8(g0, gtw + ((size_t)b*LL + c*CHN + r)*GG);
    {   // hin reconstruction
        int grp = c >> 4;
        float gh  = ghw[(((size_t)b*NGRP + grp) << 8) + tid];
        float cpv = cpw[((size_t)b*NCH + c)*2 + (tid >> 7)];
        float phv = phw[(((size_t)b*NCH + c) << 8) + tid];
        s_hin[tid] = fmaf(cpv, gh, phv);
    }
    // tile copies -> LDS
    if (tid < 64) {
        int row = tid;
        *(uint4*)&uC.Ct[row*40]      = *(const uint4*)&stC[row*8];
        *(uint4*)&uC.Ct[row*40 + 8]  = *(const uint4*)&stC[row*8 + 4];
        *(uint4*)&uC.Ct[row*40 + 16] = make_uint4(0,0,0,0);
        *(uint4*)&uC.Ct[row*40 + 24] = make_uint4(0,0,0,0);
    } else if (tid < 128) {
        int row = tid - 64;
        *(uint4*)&Bt[row*40]      = *(const uint4*)&stB[row*8];
        *(uint4*)&Bt[row*40 + 8]  = *(const uint4*)&stB[row*8 + 4];
        *(uint4*)&Bt[row*40 + 16] = make_uint4(0,0,0,0);
        *(uint4*)&Bt[row*40 + 24] = make_uint4(0,0,0,0);
    } else {
        int i = tid - 128;
        int p = i >> 3, seg = i & 7;
        *(uint4*)&XTbf[p*72 + seg*8] = *(const uint4*)&stX[p*32 + seg*4];
    }
    if (tid < 128) { s_la[tid] = stp[1536 + tid]; s_zw[tid] = ipw[tid]; }
    else s_ow[tid-128] = out_w[tid-128];
    if (tid < 16) { s_zb[tid] = ipb[tid]; s_nw[tid] = norm_w[tid]; }
    else if (tid < 24) s_ob[tid-16] = out_b[tid-16];
    __syncthreads();                                      // B0

    float D0 = Dv[0], D1 = Dv[1];
    int lane = tid & 63, wv = tid >> 6;
    int ar = lane & 15, kb = lane >> 4;
    int trow = wv*16 + kb*4;

    // ---- phase 1: G-MFMAs, Cp, hinT, exp tables ----
    f32x4 gT[4];
    {
        bf16x8 aC = *(const bf16x8*)&uC.Ct[(wv*16 + ar)*40 + kb*8];
        #pragma unroll
        for (int ss = 0; ss < 4; ++ss) {
            f32x4 g = {0.f, 0.f, 0.f, 0.f};
            if (ss <= wv) {
                bf16x8 bB = *(const bf16x8*)&Bt[(ss*16 + ar)*40 + kb*8];
                g = __builtin_amdgcn_mfma_f32_16x16x32_bf16(aC, bB, g, 0, 0, 0);
            }
            gT[ss] = g;
        }
    }
    if (tid < 128) {   // Cp = exp(la)*C, both heads
        int h = tid >> 6;
        int rr = (tid & 63);
        float sc = __expf(s_la[rr*2 + h]);
        unsigned short* Cp = h ? Cp1 : Cp0;
        unsigned int* dst = (unsigned int*)&Cp[rr*16];
        #pragma unroll
        for (int j = 0; j < 8; ++j)
            dst[j] = pack2bf(sc * bf2f(uC.Ct[rr*40 + j*2]),
                             sc * bf2f(uC.Ct[rr*40 + j*2 + 1]));
        if (tid < 32) {   // hinT build
            int i = tid;
            int hh = i >> 4, p = (i >> 1) & 7, half = i & 1;
            unsigned int wd[4];
            #pragma unroll
            for (int j = 0; j < 4; ++j)
                wd[j] = pack2bf(s_hin[hh*128 + p*16 + half*8 + 2*j],
                                s_hin[hh*128 + p*16 + half*8 + 2*j + 1]);
            *(uint4*)&hinT[hh][p*16 + half*8] = make_uint4(wd[0],wd[1],wd[2],wd[3]);
        }
    } else {           // exp tables
        int i = tid - 128;
        int h = i >> 6, s = i & 63;
        int anc = s & ~15;
        float d = s_la[anc*2 + h] - s_la[s*2 + h];
        float dtv = stp[1664 + s*2 + h];
        s_eti[h][s] = __expf(-d);
        s_etd[h][s] = __expf(d) * dtv;
        if (i < 32) {
            int h2 = i >> 4, wt = (i >> 2) & 3, ws = i & 3;
            s_esc[h2][wt][ws] = (wt >= ws) ?
                __expf(s_la[(wt*16)*2 + h2] - s_la[(ws*16)*2 + h2]) : 0.f;
        }
    }
    __syncthreads();                                      // B1

    {   // ---- phase 2: M~ both heads (table-driven, trunc-pack dword stores) ----
        float rowf0[4], rowf1[4];
        #pragma unroll
        for (int rg = 0; rg < 4; ++rg) {
            rowf0[rg] = s_eti[0][trow+rg];
            rowf1[rg] = s_eti[1][trow+rg];
        }
        #pragma unroll
        for (int ss = 0; ss < 4; ++ss) {
            int s = ss*16 + ar;
            if (ss > wv) {
                if (!(ar & 1)) {
                    #pragma unroll
                    for (int rg = 0; rg < 4; ++rg) {
                        *(unsigned int*)&M2[0][(trow+rg)*72 + ss*16 + ar] = 0u;
                        *(unsigned int*)&M2[1][(trow+rg)*72 + ss*16 + ar] = 0u;
                    }
                }
                continue;
            }
            float colf0 = s_esc[0][wv][ss] * s_etd[0][s];
            float colf1 = s_esc[1][wv][ss] * s_etd[1][s];
            #pragma unroll
            for (int rg = 0; rg < 4; ++rg) {
                bool keep = (s <= trow+rg);
                float m0 = keep ? rowf0[rg]*colf0*gT[ss][rg] : 0.f;
                float m1 = keep ? rowf1[rg]*colf1*gT[ss][rg] : 0.f;
                float m0p = __shfl_xor(m0, 1);
                float m1p = __shfl_xor(m1, 1);
                if (!(ar & 1)) {
                    *(unsigned int*)&M2[0][(trow+rg)*72 + ss*16 + ar] = packtr(m0, m0p);
                    *(unsigned int*)&M2[1][(trow+rg)*72 + ss*16 + ar] = packtr(m1, m1p);
                }
            }
        }
    }
    __syncthreads();                                      // B2

    {   // ---- phase 3: Y = M~.X + Cp.hinT, both heads; yb store (overlays Ct) ----
        int p = ar;
        f32x4 acc0 = {0.f,0.f,0.f,0.f}, acc1 = {0.f,0.f,0.f,0.f};
        #pragma unroll
        for (int kk = 0; kk < 2; ++kk) {
            bf16x8 am0 = *(const bf16x8*)&M2[0][(wv*16 + ar)*72 + kk*32 + kb*8];
            bf16x8 am1 = *(const bf16x8*)&M2[1][(wv*16 + ar)*72 + kk*32 + kb*8];
            bf16x8 bx0 = {0,0,0,0,0,0,0,0}, bx1 = {0,0,0,0,0,0,0,0};
            if (p < 8) {
                bx0 = *(const bf16x8*)&XTbf[p*72 + kk*32 + kb*8];
                bx1 = *(const bf16x8*)&XTbf[(8+p)*72 + kk*32 + kb*8];
            }
            acc0 = __builtin_amdgcn_mfma_f32_16x16x32_bf16(am0, bx0, acc0, 0, 0, 0);
            acc1 = __builtin_amdgcn_mfma_f32_16x16x32_bf16(am1, bx1, acc1, 0, 0, 0);
        }
        bf16x8 aCp0 = {0,0,0,0,0,0,0,0}, aCp1 = {0,0,0,0,0,0,0,0};
        bf16x8 bh0 = {0,0,0,0,0,0,0,0}, bh1 = {0,0,0,0,0,0,0,0};
        if (kb < 2) {
            aCp0 = *(const bf16x8*)&Cp0[(wv*16 + ar)*16 + kb*8];
            aCp1 = *(const bf16x8*)&Cp1[(wv*16 + ar)*16 + kb*8];
            if (ar < 8) {
                bh0 = *(const bf16x8*)&hinT[0][ar*16 + kb*8];
                bh1 = *(const bf16x8*)&hinT[1][ar*16 + kb*8];
            }
        }
        acc0 = __builtin_amdgcn_mfma_f32_16x16x32_bf16(aCp0, bh0, acc0, 0, 0, 0);
        acc1 = __builtin_amdgcn_mfma_f32_16x16x32_bf16(aCp1, bh1, acc1, 0, 0, 0);
        if (p < 8) {
            #pragma unroll
            for (int rg = 0; rg < 4; ++rg) {
                int t = trow + rg;
                uC.yb[t*20 + p]     = fmaf(D0, bf2f(XTbf[p*72 + t]),     acc0[rg]);
                uC.yb[t*20 + 8 + p] = fmaf(D1, bf2f(XTbf[(8+p)*72 + t]), acc1[rg]);
            }
        }
    }
    __syncthreads();                                      // B3

    {   // ---- phase 4: epilogue ----
        int q = sub;
        float vv[4]; float ssq = 0.f;
        #pragma unroll
        for (int j = 0; j < 4; ++j) {
            int hp = q*4 + j;
            float zz = s_zb[hp];
            #pragma unroll
            for (int g = 0; g < 8; ++g) zz = fmaf(g0[g], s_zw[hp*8+g], zz);
            float y = uC.yb[r*20 + hp];
            float w = y * siluf(zz);
            vv[j] = w; ssq = fmaf(w, w, ssq);
        }
        ssq += __shfl_xor(ssq, 1);
        ssq += __shfl_xor(ssq, 2);
        float rn = rsqrtf(ssq*(1.f/16.f) + 1e-5f);
        float o[8];
        #pragma unroll
        for (int g = 0; g < 8; ++g) o[g] = 0.f;
        #pragma unroll
        for (int j = 0; j < 4; ++j) {
            float wj = vv[j] * rn * s_nw[q*4+j];
            #pragma unroll
            for (int g = 0; g < 8; ++g) o[g] = fmaf(wj, s_ow[g*16 + q*4 + j], o[g]);
        }
        #pragma unroll
        for (int g = 0; g < 8; ++g) {
            o[g] += __shfl_xor(o[g], 1);
            o[g] += __shfl_xor(o[g], 2);
        }
        if (q == 0) {
            #pragma unroll
            for (int g = 0; g < 8; ++g) o[g] += s_ob[g] + g0[g];
            float* gp = g2w + ((size_t)b*LL + c*CHN + r)*GG;
            ((float4*)gp)[0] = make_float4(o[0],o[1],o[2],o[3]);
            ((float4*)gp)[1] = make_float4(o[4],o[5],o[6],o[7]);
        }
    }
}

// K5b: out = x + detok(g2) + detok_b.
__global__ __launch_bounds__(64) void k5b_detok(
    const float* __restrict__ x, const float* __restrict__ g2w,
    const float* __restrict__ dkw, const float* __restrict__ dkb,
    float* __restrict__ outp)
{
    __shared__ float s_dw[CF*GG];
    __shared__ float s_db[CF];
    int tid = threadIdx.x;
    int b  = blockIdx.x >> 6;
    int ck = blockIdx.x & 63;
    int l0 = (ck << 8) + (tid << 2);
    for (int i = tid; i < CF*GG; i += 64) s_dw[i] = dkw[i];
    s_db[tid] = dkb[tid];
    __syncthreads();
    float g2v[4][8];
    const float* gp = g2w + ((size_t)b*LL + l0)*GG;
    #pragma unroll
    for (int r = 0; r < 4; ++r) load8(g2v[r], gp + r*GG);
    const float* xb = x + (size_t)b*CF*LL + l0;
    float* ob = outp + (size_t)b*CF*LL + l0;
    #pragma unroll 4
    for (int c = 0; c < CF; ++c) {
        float4 xv = *(const float4*)(xb + (size_t)c*LL);
        float bias = s_db[c];
        float oa[4] = {xv.x+bias, xv.y+bias, xv.z+bias, xv.w+bias};
        #pragma unroll
        for (int g = 0; g < GG; ++g) {
            float w = s_dw[c*GG+g];
            #pragma unroll
            for (int r = 0; r < 4; ++r) oa[r] = fmaf(g2v[r][g], w, oa[r]);
        }
        *(float4*)(ob + (size_t)c*LL) = make_float4(oa[0],oa[1],oa[2],oa[3]);
    }
}

extern "C" void kernel_launch(void* const* d_in, const int* in_sizes, int n_in,
                              void* d_out, int out_size, void* d_ws, size_t ws_size,
                              hipStream_t stream) {
    const float* x       = (const float*)d_in[0];
    const float* tok_w   = (const float*)d_in[1];
    const float* tok_b   = (const float*)d_in[2];
    const float* detok_w = (const float*)d_in[3];
    const float* detok_b = (const float*)d_in[4];
    const float* ipw     = (const float*)d_in[5];
    const float* ipb     = (const float*)d_in[6];
    const float* cw      = (const float*)d_in[7];
    const float* cb      = (const float*)d_in[8];
    const float* A_log   = (const float*)d_in[9];
    const float* Dv      = (const float*)d_in[10];
    const float* dt_bias = (const float*)d_in[11];
    const float* norm_w  = (const float*)d_in[12];
    const float* out_w   = (const float*)d_in[13];
    const float* out_b   = (const float*)d_in[14];
    float* ws = (float*)d_ws;
    float* outp = (float*)d_out;

    if (ws_size < WS_FLOATS * sizeof(float)) return;

    k1a_tok<<<NB*64, 64, 0, stream>>>(x, tok_w, tok_b, ws+OFF_GT);
    k2a_state<<<NB*NCH, 256, 0, stream>>>(ws+OFF_GT, ipw, ipb, cw, cb,
        A_log, dt_bias, ws+OFF_ST, ws+OFF_U2, ws+OFF_AC);
    k4c1<<<NB*NGRP, 256, 0, stream>>>(ws+OFF_U2, ws+OFF_AC,
        ws+OFF_PH, ws+OFF_CP, ws+OFF_UG, ws+OFF_AG);
    k4c2<<<NB, 256, 0, stream>>>(ws+OFF_UG, ws+OFF_AG, ws+OFF_GH);
    k2b_fused<<<NB*NCH, 256, 0, stream>>>(ws+OFF_GT, ipw, ipb,
        Dv, norm_w, out_w, out_b,
        ws+OFF_PH, ws+OFF_CP, ws+OFF_GH, ws+OFF_ST, ws+OFF_G2);
    k5b_detok<<<NB*64, 64, 0, stream>>>(x, ws+OFF_G2, detok_w, detok_b, outp);
}

// Round 13
// 118.622 us; speedup vs baseline: 1.1330x; 1.0301x over previous
//
#include <hip/hip_runtime.h>
#include <math.h>

#define NB 16
#define CF 64
#define LL 16384
#define GG 8
#define NH 2
#define CHN 64
#define NCH 256
#define NGRP 16

static constexpr size_t OFF_GT = 0;
static constexpr size_t OFF_U2 = OFF_GT + (size_t)NB*LL*GG;
static constexpr size_t OFF_AC = OFF_U2 + (size_t)NB*NCH*256;
static constexpr size_t OFF_PH = OFF_AC + (size_t)NB*NCH*NH;
static constexpr size_t OFF_CP = OFF_PH + (size_t)NB*NCH*256;
static constexpr size_t OFF_UG = OFF_CP + (size_t)NB*NCH*NH;
static constexpr size_t OFF_AG = OFF_UG + (size_t)NB*NGRP*256;
static constexpr size_t OFF_GH = OFF_AG + (size_t)NB*NGRP*NH;
static constexpr size_t OFF_G2 = OFF_GH + (size_t)NB*NGRP*256;
static constexpr size_t OFF_ST = OFF_G2 + (size_t)NB*LL*GG;
// per-chunk staged record: 1792 floats = XT[512] B[512] C[512] la[128] dt[128]
static constexpr size_t WS_FLOATS = OFF_ST + (size_t)NB*NCH*1792;

typedef float f32x4 __attribute__((ext_vector_type(4)));
typedef short bf16x8 __attribute__((ext_vector_type(8)));

__device__ __forceinline__ float siluf(float v){ return v / (1.f + __expf(-v)); }
__device__ __forceinline__ float softplusf(float v){ return v > 20.f ? v : log1pf(__expf(v)); }

__device__ __forceinline__ unsigned short f2bf(float f){
    unsigned int u = __float_as_uint(f);
    u += 0x7fffu + ((u >> 16) & 1u);
    return (unsigned short)(u >> 16);
}
__device__ __forceinline__ float bf2f(unsigned short s){
    return __uint_as_float(((unsigned int)s) << 16);
}
__device__ __forceinline__ unsigned int pack2bf(float lo, float hi){
    return (unsigned int)f2bf(lo) | ((unsigned int)f2bf(hi) << 16);
}
__device__ __forceinline__ unsigned int packtr(float lo, float hi){
    return (__float_as_uint(hi) & 0xffff0000u) | (__float_as_uint(lo) >> 16);
}

__device__ __forceinline__ void load8(float* d, const float* p){
    float4 a = ((const float4*)p)[0];
    float4 b = ((const float4*)p)[1];
    d[0]=a.x; d[1]=a.y; d[2]=a.z; d[3]=a.w;
    d[4]=b.x; d[5]=b.y; d[6]=b.z; d[7]=b.w;
}

// K1a: tokenize x -> gt.
__global__ __launch_bounds__(64) void k1a_tok(
    const float* __restrict__ x, const float* __restrict__ tok_w,
    const float* __restrict__ tok_b, float* __restrict__ gtw)
{
    __shared__ float s_tok[GG*CF];
    int tid = threadIdx.x;
    int b  = blockIdx.x >> 6;
    int ck = blockIdx.x & 63;
    int l0 = (ck << 8) + (tid << 2);
    for (int i = tid; i < GG*CF; i += 64) s_tok[i] = tok_w[i];
    __syncthreads();
    float acc[4][GG];
    #pragma unroll
    for (int r = 0; r < 4; ++r)
        #pragma unroll
        for (int g = 0; g < GG; ++g) acc[r][g] = tok_b[g];
    const float* xb = x + (size_t)b*CF*LL + l0;
    #pragma unroll 8
    for (int c = 0; c < CF; ++c) {
        float4 xv = *(const float4*)(xb + (size_t)c*LL);
        float xa[4] = {xv.x, xv.y, xv.z, xv.w};
        #pragma unroll
        for (int g = 0; g < GG; ++g) {
            float w = s_tok[g*CF + c];
            #pragma unroll
            for (int r = 0; r < 4; ++r) acc[r][g] = fmaf(xa[r], w, acc[r][g]);
        }
    }
    float* gp = gtw + ((size_t)b*LL + l0)*GG;
    #pragma unroll
    for (int r = 0; r < 4; ++r) {
        ((float4*)gp)[r*2+0] = make_float4(acc[r][0],acc[r][1],acc[r][2],acc[r][3]);
        ((float4*)gp)[r*2+1] = make_float4(acc[r][4],acc[r][5],acc[r][6],acc[r][7]);
    }
}

// Shared W-build: combined conv+in_proj weight W[64][32] bf16, bias2, boundary corr.
__device__ __forceinline__ void build_W(
    int tid, const float* ipw, const float* ipb, const float* cw, const float* cb,
    unsigned short* Wt, float* s_bias, float* s_c0, float* s_c1, float* s_wdt)
{
    int col = tid & 63, kb = tid >> 6;
    unsigned int wd0=0u, wd1=0u, wd2=0u, wd3=0u;
    if (col < 48) {
        if (kb < 3) {
            float cwv = cw[col*3 + (2-kb)];
            const float* iprow = ipw + (16+col)*8;
            wd0 = pack2bf(iprow[0]*cwv, iprow[1]*cwv);
            wd1 = pack2bf(iprow[2]*cwv, iprow[3]*cwv);
            wd2 = pack2bf(iprow[4]*cwv, iprow[5]*cwv);
            wd3 = pack2bf(iprow[6]*cwv, iprow[7]*cwv);
        }
    } else if (kb == 0) {
        const float* iprow = ipw + (col-48)*8;
        wd0 = pack2bf(iprow[0], iprow[1]);
        wd1 = pack2bf(iprow[2], iprow[3]);
        wd2 = pack2bf(iprow[4], iprow[5]);
        wd3 = pack2bf(iprow[6], iprow[7]);
    }
    *(uint4*)&Wt[col*32 + kb*8] = make_uint4(wd0,wd1,wd2,wd3);
    if (kb == 0) {
        float bias;
        if (col < 48) {
            float w0 = cw[col*3], w1 = cw[col*3+1], w2 = cw[col*3+2];
            float ib = ipb[16+col];
            bias = cb[col] + ib*(w0+w1+w2);
            s_c0[col] = ib*(w0+w1);
            s_c1[col] = ib*w0;
        } else bias = ipb[col-48];
        s_bias[col] = bias;
    } else if (kb == 1 && col < 16) s_wdt[col] = ipw[512 + col];
}

// K2a: MFMA staging -> persist XT/Brow/Crow/la/dt; cumsum; WX; state MFMA -> U2, Ac.
__global__ __launch_bounds__(256) void k2a_state(
    const float* __restrict__ gtw,
    const float* __restrict__ ipw, const float* __restrict__ ipb,
    const float* __restrict__ cw, const float* __restrict__ cb,
    const float* __restrict__ A_log, const float* __restrict__ dt_bias,
    float* __restrict__ stw,
    float* __restrict__ U2w, float* __restrict__ Acw)
{
    __shared__ __align__(16) unsigned short Wt[64*32];
    __shared__ float s_bias[64], s_c0[48], s_c1[48], s_wdt[16];
    __shared__ __align__(16) unsigned short XTbf[16*72];   // x^T [p][s]
    __shared__ __align__(16) unsigned short BTbf[16*72];   // B^T [n][s]
    __shared__ __align__(16) unsigned short WXbf[16*72];   // (w*x)^T
    __shared__ __align__(16) unsigned short Brow[64*16];   // B row-major
    __shared__ __align__(16) unsigned short Crow[64*16];   // C row-major
    __shared__ float s_dt[64][2], s_nda[64][2], s_w[64][2];

    int tid = threadIdx.x;
    int b = blockIdx.x >> 8, c = blockIdx.x & 255;
    float* stp = stw + ((size_t)(b*NCH + c))*1792;
    build_W(tid, ipw, ipb, cw, cb, Wt, s_bias, s_c0, s_c1, s_wdt);
    __syncthreads();                                    // B0

    float a0e = __expf(A_log[0]), a1e = __expf(A_log[1]);
    float dtb0 = dt_bias[0], dtb1 = dt_bias[1];
    float bdt0 = ipb[64], bdt1 = ipb[65];

    int lane = tid & 63, wv = tid >> 6;
    int ar = lane & 15, kb = lane >> 4;
    int trow = wv*16 + kb*4;

    // staging MFMA: A from gt (rows shifted by kb); x, B, C column tiles
    float fr[8];
    bf16x8 aop = {0,0,0,0,0,0,0,0};
    int rowi = c*CHN + wv*16 + ar - kb;
    if (kb < 3 && rowi >= 0) {
        load8(fr, gtw + ((size_t)b*LL + rowi)*GG);
        unsigned int* ap = (unsigned int*)&aop;
        ap[0] = pack2bf(fr[0],fr[1]); ap[1] = pack2bf(fr[2],fr[3]);
        ap[2] = pack2bf(fr[4],fr[5]); ap[3] = pack2bf(fr[6],fr[7]);
    }
    f32x4 st0, st1, st2;
    {
        float b0 = s_bias[ar], b1 = s_bias[16+ar], b2 = s_bias[32+ar];
        f32x4 c0v = {b0,b0,b0,b0}, c1v = {b1,b1,b1,b1}, c2v = {b2,b2,b2,b2};
        st0 = __builtin_amdgcn_mfma_f32_16x16x32_bf16(aop, *(const bf16x8*)&Wt[ar*32 + kb*8],      c0v, 0,0,0);
        st1 = __builtin_amdgcn_mfma_f32_16x16x32_bf16(aop, *(const bf16x8*)&Wt[(16+ar)*32 + kb*8], c1v, 0,0,0);
        st2 = __builtin_amdgcn_mfma_f32_16x16x32_bf16(aop, *(const bf16x8*)&Wt[(32+ar)*32 + kb*8], c2v, 0,0,0);
    }
    if (c == 0 && wv == 0 && kb == 0) {    // chunk-0 boundary fixup (rows 0,1)
        st0[0] -= s_c0[ar];    st0[1] -= s_c1[ar];
        st1[0] -= s_c0[16+ar]; st1[1] -= s_c1[16+ar];
        st2[0] -= s_c0[32+ar]; st2[1] -= s_c1[32+ar];
    }
    if (kb == 0) {                          // dt for row wv*16+ar (fp32-exact)
        float d0 = bdt0, d1 = bdt1;
        #pragma unroll
        for (int g = 0; g < 8; ++g) {
            d0 = fmaf(fr[g], s_wdt[g],   d0);
            d1 = fmaf(fr[g], s_wdt[8+g], d1);
        }
        float dt0 = softplusf(d0 + dtb0), dt1 = softplusf(d1 + dtb1);
        int row = wv*16 + ar;
        s_dt[row][0] = dt0; s_dt[row][1] = dt1;
        s_nda[row][0] = -dt0*a0e; s_nda[row][1] = -dt1*a1e;
    }
    {   // x -> XT (b64); B -> BT (b64); B,C -> row tiles via shfl-pair dwords
        float v0 = siluf(st0[0]), v1 = siluf(st0[1]), v2 = siluf(st0[2]), v3 = siluf(st0[3]);
        *(uint2*)&XTbf[ar*72 + trow] = make_uint2(pack2bf(v0,v1), pack2bf(v2,v3));
        float b0 = siluf(st1[0]), b1 = siluf(st1[1]), b2 = siluf(st1[2]), b3 = siluf(st1[3]);
        *(uint2*)&BTbf[ar*72 + trow] = make_uint2(pack2bf(b0,b1), pack2bf(b2,b3));
        float bb[4] = {b0,b1,b2,b3};
        #pragma unroll
        for (int rg = 0; rg < 4; ++rg) {
            float vB = bb[rg];
            float vC = siluf(st2[rg]);
            float pB = __shfl_xor(vB, 1);
            float pC = __shfl_xor(vC, 1);
            if (!(ar & 1)) {
                *(unsigned int*)&Brow[(trow+rg)*16 + ar] = pack2bf(vB, pB);
                *(unsigned int*)&Crow[(trow+rg)*16 + ar] = pack2bf(vC, pC);
            }
        }
    }
    __syncthreads();                                    // B1

    if (tid < 64) {   // cumsum + weights + la/dt persist + Ac
        int rr = tid;
        float v0 = s_nda[rr][0], v1 = s_nda[rr][1];
        #pragma unroll
        for (int off = 1; off < 64; off <<= 1) {
            float t0 = __shfl_up(v0, off);
            float t1 = __shfl_up(v1, off);
            if (rr >= off) { v0 += t0; v1 += t1; }
        }
        float f0 = __shfl(v0, 63), f1 = __shfl(v1, 63);
        s_w[rr][0] = __expf(f0 - v0) * s_dt[rr][0];
        s_w[rr][1] = __expf(f1 - v1) * s_dt[rr][1];
        stp[1536 + rr*2 + 0] = v0;
        stp[1536 + rr*2 + 1] = v1;
        stp[1664 + rr*2 + 0] = s_dt[rr][0];
        stp[1664 + rr*2 + 1] = s_dt[rr][1];
        if (rr == 63)
            *(float2*)(Acw + ((size_t)b*NCH + c)*2) = make_float2(__expf(f0), __expf(f1));
    }
    __syncthreads();                                    // B2

    {   // WX build (tid<128) || XT persist (tid>=128); then Brow/Crow persist
        unsigned int* stX = (unsigned int*)stp;
        unsigned int* stB = (unsigned int*)(stp + 512);
        unsigned int* stC = (unsigned int*)(stp + 1024);
        if (tid < 128) {
            int p = tid >> 3, seg = tid & 7;
            int s0 = seg*8, he = p >> 3;
            const unsigned short* xp = &XTbf[p*72 + s0];
            unsigned int wd[4];
            #pragma unroll
            for (int j = 0; j < 4; ++j) {
                float lo = bf2f(xp[2*j])   * s_w[s0+2*j][he];
                float hi = bf2f(xp[2*j+1]) * s_w[s0+2*j+1][he];
                wd[j] = pack2bf(lo, hi);
            }
            *(uint4*)&WXbf[p*72 + s0] = make_uint4(wd[0],wd[1],wd[2],wd[3]);
            int row = tid >> 1, hf = tid & 1;
            *(uint4*)&stB[row*8 + hf*4] = *(const uint4*)&Brow[row*16 + hf*8];
        } else {
            int i = tid - 128;
            int p = i >> 3, seg = i & 7;
            *(uint4*)&stX[p*32 + seg*4] = *(const uint4*)&XTbf[p*72 + seg*8];
            int row = i >> 1, hf = i & 1;
            *(uint4*)&stC[row*8 + hf*4] = *(const uint4*)&Crow[row*16 + hf*8];
        }
    }
    __syncthreads();                                    // B3

    if (tid < 64) {
        int ar2 = tid & 15, kb2 = tid >> 4;
        f32x4 acc = {0.f, 0.f, 0.f, 0.f};
        #pragma unroll
        for (int kk = 0; kk < 2; ++kk) {
            bf16x8 aw = *(const bf16x8*)&WXbf[ar2*72 + kk*32 + kb2*8];
            bf16x8 bb = *(const bf16x8*)&BTbf[ar2*72 + kk*32 + kb2*8];
            acc = __builtin_amdgcn_mfma_f32_16x16x32_bf16(aw, bb, acc, 0, 0, 0);
        }
        #pragma unroll
        for (int rg = 0; rg < 4; ++rg)
            U2w[(((size_t)b*NCH + c) << 8) + (kb2*4+rg)*16 + ar2] = acc[rg];
    }
}

// K4c1: scan 16 chunks within each group.
__global__ void k4c1(const float* __restrict__ U2w, const float* __restrict__ Acw,
                     float* __restrict__ phw, float* __restrict__ cpw,
                     float* __restrict__ Ugw, float* __restrict__ Agw)
{
    int b = blockIdx.x >> 4, grp = blockIdx.x & 15;
    int e = threadIdx.x, he = e >> 7;
    size_t base = (size_t)b*NCH + grp*16;
    float u[16], A[16];
    #pragma unroll
    for (int j = 0; j < 16; ++j) u[j] = U2w[((base + j) << 8) + e];
    #pragma unroll
    for (int j = 0; j < 16; ++j) A[j] = Acw[(base + j)*2 + he];
    float h = 0.f, cp = 1.f;
    #pragma unroll
    for (int j = 0; j < 16; ++j) {
        phw[((base + j) << 8) + e] = h;
        if ((e & 127) == 0) cpw[(base + j)*2 + he] = cp;
        h = fmaf(A[j], h, u[j]);
        cp *= A[j];
    }
    Ugw[(((size_t)b*NGRP + grp) << 8) + e] = h;
    if ((e & 127) == 0) Agw[((size_t)b*NGRP + grp)*2 + he] = cp;
}

// K4c2: scan 16 group summaries.
__global__ void k4c2(const float* __restrict__ Ugw, const float* __restrict__ Agw,
                     float* __restrict__ ghw)
{
    int b = blockIdx.x, e = threadIdx.x, he = e >> 7;
    float u[NGRP], ag[NGRP];
    #pragma unroll
    for (int g = 0; g < NGRP; ++g) {
        u[g]  = Ugw[(((size_t)b*NGRP + g) << 8) + e];
        ag[g] = Agw[((size_t)b*NGRP + g)*2 + he];
    }
    float h = 0.f;
    #pragma unroll
    for (int g = 0; g < NGRP; ++g) {
        ghw[(((size_t)b*NGRP + g) << 8) + e] = h;
        h = fmaf(ag[g], h, u[g]);
    }
}

// K2b: consume staged tiles (A/B operands direct from L2) -> G, M~ per head,
// Y + hin correction, epilogue -> g2.  Slim LDS (~25 KB) for 6 blocks/CU.
__global__ __launch_bounds__(256) void k2b_fused(
    const float* __restrict__ gtw,
    const float* __restrict__ ipw, const float* __restrict__ ipb,
    const float* __restrict__ Dv, const float* __restrict__ norm_w,
    const float* __restrict__ out_w, const float* __restrict__ out_b,
    const float* __restrict__ phw, const float* __restrict__ cpw,
    const float* __restrict__ ghw, const float* __restrict__ stw,
    float* __restrict__ g2w)
{
    __shared__ float yb[64*20];
    __shared__ __align__(16) unsigned short XTbf[16*72];
    __shared__ __align__(16) unsigned short Mb[64*72];
    __shared__ __align__(16) unsigned short Cp0[64*16], Cp1[64*16];
    __shared__ __align__(16) unsigned short hinT[2][8*16];
    __shared__ float s_hin[256];
    __shared__ float s_la[128];
    __shared__ float s_eti[2][64], s_etd[2][64], s_esc[2][4][4];
    __shared__ float s_zw[128], s_ow[128], s_zb[16], s_nw[16], s_ob[8];

    int tid = threadIdx.x;
    int b = blockIdx.x >> 8, c = blockIdx.x & 255;
    const float* stp = stw + ((size_t)(b*NCH + c))*1792;
    const unsigned int* stX = (const unsigned int*)stp;
    const unsigned short* stBu = (const unsigned short*)(stp + 512);
    const unsigned short* stCu = (const unsigned short*)(stp + 1024);

    int r = tid >> 2, sub = tid & 3;
    int lane = tid & 63, wv = tid >> 6;
    int ar = lane & 15, kb = lane >> 4;
    int trow = wv*16 + kb*4;

    float g0[8];
    load8(g0, gtw + ((size_t)b*LL + c*CHN + r)*GG);

    // G operands straight from staged global (L2) -> registers; MFMA before B0.
    bf16x8 aC = {0,0,0,0,0,0,0,0};
    bf16x8 bBr[4];
    #pragma unroll
    for (int ss = 0; ss < 4; ++ss) bBr[ss] = (bf16x8){0,0,0,0,0,0,0,0};
    if (kb < 2) {
        aC = *(const bf16x8*)&stCu[(wv*16 + ar)*16 + kb*8];
        #pragma unroll
        for (int ss = 0; ss < 4; ++ss)
            if (ss <= wv) bBr[ss] = *(const bf16x8*)&stBu[(ss*16 + ar)*16 + kb*8];
    }
    f32x4 gT[4];
    #pragma unroll
    for (int ss = 0; ss < 4; ++ss) {
        f32x4 g = {0.f, 0.f, 0.f, 0.f};
        if (ss <= wv)
            g = __builtin_amdgcn_mfma_f32_16x16x32_bf16(aC, bBr[ss], g, 0, 0, 0);
        gT[ss] = g;
    }

    {   // hin reconstruction
        int grp = c >> 4;
        float gh  = ghw[(((size_t)b*NGRP + grp) << 8) + tid];
        float cpv = cpw[((size_t)b*NCH + c)*2 + (tid >> 7)];
        float phv = phw[(((size_t)b*NCH + c) << 8) + tid];
        s_hin[tid] = fmaf(cpv, gh, phv);
    }
    if (tid < 128) {   // XT copy + la + zw
        int p = tid >> 3, seg = tid & 7;
        *(uint4*)&XTbf[p*72 + seg*8] = *(const uint4*)&stX[p*32 + seg*4];
        s_la[tid] = stp[1536 + tid];
        s_zw[tid] = ipw[tid];
    } else {
        s_ow[tid-128] = out_w[tid-128];
        int t2 = tid - 128;
        if (t2 < 16) { s_zb[t2] = ipb[t2]; s_nw[t2] = norm_w[t2]; }
        else if (t2 < 24) s_ob[t2-16] = out_b[t2-16];
    }
    __syncthreads();                                      // B0

    float D0 = Dv[0], D1 = Dv[1];

    // ---- phase 1: Cp (from global C rows) + hinT (tid<128) || exp tables ----
    if (tid < 128) {
        int h = tid >> 6;
        int rr = tid & 63;
        float sc = __expf(s_la[rr*2 + h]);
        uint4 ra = *(const uint4*)&stCu[rr*16];
        uint4 rb = *(const uint4*)&stCu[rr*16 + 8];
        unsigned int src[8] = {ra.x,ra.y,ra.z,ra.w, rb.x,rb.y,rb.z,rb.w};
        unsigned short* Cp = h ? Cp1 : Cp0;
        unsigned int* dst = (unsigned int*)&Cp[rr*16];
        #pragma unroll
        for (int j = 0; j < 8; ++j) {
            float lo = bf2f((unsigned short)(src[j] & 0xffffu)) * sc;
            float hi = bf2f((unsigned short)(src[j] >> 16)) * sc;
            dst[j] = pack2bf(lo, hi);
        }
        if (tid < 32) {   // hinT build
            int i = tid;
            int hh = i >> 4, p = (i >> 1) & 7, half = i & 1;
            unsigned int wd[4];
            #pragma unroll
            for (int j = 0; j < 4; ++j)
                wd[j] = pack2bf(s_hin[hh*128 + p*16 + half*8 + 2*j],
                                s_hin[hh*128 + p*16 + half*8 + 2*j + 1]);
            *(uint4*)&hinT[hh][p*16 + half*8] = make_uint4(wd[0],wd[1],wd[2],wd[3]);
        }
    } else {           // exp tables
        int i = tid - 128;
        int h = i >> 6, s = i & 63;
        int anc = s & ~15;
        float d = s_la[anc*2 + h] - s_la[s*2 + h];
        float dtv = stp[1664 + s*2 + h];
        s_eti[h][s] = __expf(-d);
        s_etd[h][s] = __expf(d) * dtv;
        if (i < 32) {
            int h2 = i >> 4, wt = (i >> 2) & 3, ws = i & 3;
            s_esc[h2][wt][ws] = (wt >= ws) ?
                __expf(s_la[(wt*16)*2 + h2] - s_la[(ws*16)*2 + h2]) : 0.f;
        }
    }
    __syncthreads();                                      // B1

    #pragma unroll
    for (int h = 0; h < 2; ++h) {
        {   // ---- M~ head h (table-driven, trunc-pack dword stores) ----
            float rowf[4];
            #pragma unroll
            for (int rg = 0; rg < 4; ++rg) rowf[rg] = s_eti[h][trow+rg];
            #pragma unroll
            for (int ss = 0; ss < 4; ++ss) {
                int s = ss*16 + ar;
                if (ss > wv) {
                    if (!(ar & 1)) {
                        #pragma unroll
                        for (int rg = 0; rg < 4; ++rg)
                            *(unsigned int*)&Mb[(trow+rg)*72 + ss*16 + ar] = 0u;
                    }
                    continue;
                }
                float colf = s_esc[h][wv][ss] * s_etd[h][s];
                #pragma unroll
                for (int rg = 0; rg < 4; ++rg) {
                    bool keep = (s <= trow+rg);
                    float m = keep ? rowf[rg]*colf*gT[ss][rg] : 0.f;
                    float mp = __shfl_xor(m, 1);
                    if (!(ar & 1))
                        *(unsigned int*)&Mb[(trow+rg)*72 + ss*16 + ar] = packtr(m, mp);
                }
            }
        }
        __syncthreads();                                  // B2 / B4

        {   // ---- Y head h = M~.X + Cp.hinT; yb store ----
            int p = ar;
            f32x4 acc = {0.f,0.f,0.f,0.f};
            #pragma unroll
            for (int kk = 0; kk < 2; ++kk) {
                bf16x8 am = *(const bf16x8*)&Mb[(wv*16 + ar)*72 + kk*32 + kb*8];
                bf16x8 bx = {0,0,0,0,0,0,0,0};
                if (p < 8) bx = *(const bf16x8*)&XTbf[(h*8 + p)*72 + kk*32 + kb*8];
                acc = __builtin_amdgcn_mfma_f32_16x16x32_bf16(am, bx, acc, 0, 0, 0);
            }
            bf16x8 aCp = {0,0,0,0,0,0,0,0};
            bf16x8 bh  = {0,0,0,0,0,0,0,0};
            if (kb < 2) {
                aCp = h ? *(const bf16x8*)&Cp1[(wv*16 + ar)*16 + kb*8]
                        : *(const bf16x8*)&Cp0[(wv*16 + ar)*16 + kb*8];
                if (ar < 8) bh = *(const bf16x8*)&hinT[h][ar*16 + kb*8];
            }
            acc = __builtin_amdgcn_mfma_f32_16x16x32_bf16(aCp, bh, acc, 0, 0, 0);
            if (p < 8) {
                float Dh = h ? D1 : D0;
                #pragma unroll
                for (int rg = 0; rg < 4; ++rg) {
                    int t = trow + rg;
                    yb[t*20 + h*8 + p] = fmaf(Dh, bf2f(XTbf[(h*8 + p)*72 + t]), acc[rg]);
                }
            }
        }
        __syncthreads();                                  // B3 / B5
    }

    {   // ---- epilogue ----
        int q = sub;
        float vv[4]; float ssq = 0.f;
        #pragma unroll
        for (int j = 0; j < 4; ++j) {
            int hp = q*4 + j;
            float zz = s_zb[hp];
            #pragma unroll
            for (int g = 0; g < 8; ++g) zz = fmaf(g0[g], s_zw[hp*8+g], zz);
            float y = yb[r*20 + hp];
            float w = y * siluf(zz);
            vv[j] = w; ssq = fmaf(w, w, ssq);
        }
        ssq += __shfl_xor(ssq, 1);
        ssq += __shfl_xor(ssq, 2);
        float rn = rsqrtf(ssq*(1.f/16.f) + 1e-5f);
        float o[8];
        #pragma unroll
        for (int g = 0; g < 8; ++g) o[g] = 0.f;
        #pragma unroll
        for (int j = 0; j < 4; ++j) {
            float wj = vv[j] * rn * s_nw[q*4+j];
            #pragma unroll
            for (int g = 0; g < 8; ++g) o[g] = fmaf(wj, s_ow[g*16 + q*4 + j], o[g]);
        }
        #pragma unroll
        for (int g = 0; g < 8; ++g) {
            o[g] += __shfl_xor(o[g], 1);
            o[g] += __shfl_xor(o[g], 2);
        }
        if (q == 0) {
            #pragma unroll
            for (int g = 0; g < 8; ++g) o[g] += s_ob[g] + g0[g];
            float* gp = g2w + ((size_t)b*LL + c*CHN + r)*GG;
            ((float4*)gp)[0] = make_float4(o[0],o[1],o[2],o[3]);
            ((float4*)gp)[1] = make_float4(o[4],o[5],o[6],o[7]);
        }
    }
}

// K5b: out = x + detok(g2) + detok_b.
__global__ __launch_bounds__(64) void k5b_detok(
    const float* __restrict__ x, const float* __restrict__ g2w,
    const float* __restrict__ dkw, const float* __restrict__ dkb,
    float* __restrict__ outp)
{
    __shared__ float s_dw[CF*GG];
    __shared__ float s_db[CF];
    int tid = threadIdx.x;
    int b  = blockIdx.x >> 6;
    int ck = blockIdx.x & 63;
    int l0 = (ck << 8) + (tid << 2);
    for (int i = tid; i < CF*GG; i += 64) s_dw[i] = dkw[i];
    s_db[tid] = dkb[tid];
    __syncthreads();
    float g2v[4][8];
    const float* gp = g2w + ((size_t)b*LL + l0)*GG;
    #pragma unroll
    for (int r = 0; r < 4; ++r) load8(g2v[r], gp + r*GG);
    const float* xb = x + (size_t)b*CF*LL + l0;
    float* ob = outp + (size_t)b*CF*LL + l0;
    #pragma unroll 4
    for (int c = 0; c < CF; ++c) {
        float4 xv = *(const float4*)(xb + (size_t)c*LL);
        float bias = s_db[c];
        float oa[4] = {xv.x+bias, xv.y+bias, xv.z+bias, xv.w+bias};
        #pragma unroll
        for (int g = 0; g < GG; ++g) {
            float w = s_dw[c*GG+g];
            #pragma unroll
            for (int r = 0; r < 4; ++r) oa[r] = fmaf(g2v[r][g], w, oa[r]);
        }
        *(float4*)(ob + (size_t)c*LL) = make_float4(oa[0],oa[1],oa[2],oa[3]);
    }
}

extern "C" void kernel_launch(void* const* d_in, const int* in_sizes, int n_in,
                              void* d_out, int out_size, void* d_ws, size_t ws_size,
                              hipStream_t stream) {
    const float* x       = (const float*)d_in[0];
    const float* tok_w   = (const float*)d_in[1];
    const float* tok_b   = (const float*)d_in[2];
    const float* detok_w = (const float*)d_in[3];
    const float* detok_b = (const float*)d_in[4];
    const float* ipw     = (const float*)d_in[5];
    const float* ipb     = (const float*)d_in[6];
    const float* cw      = (const float*)d_in[7];
    const float* cb      = (const float*)d_in[8];
    const float* A_log   = (const float*)d_in[9];
    const float* Dv      = (const float*)d_in[10];
    const float* dt_bias = (const float*)d_in[11];
    const float* norm_w  = (const float*)d_in[12];
    const float* out_w   = (const float*)d_in[13];
    const float* out_b   = (const float*)d_in[14];
    float* ws = (float*)d_ws;
    float* outp = (float*)d_out;

    if (ws_size < WS_FLOATS * sizeof(float)) return;

    k1a_tok<<<NB*64, 64, 0, stream>>>(x, tok_w, tok_b, ws+OFF_GT);
    k2a_state<<<NB*NCH, 256, 0, stream>>>(ws+OFF_GT, ipw, ipb, cw, cb,
        A_log, dt_bias, ws+OFF_ST, ws+OFF_U2, ws+OFF_AC);
    k4c1<<<NB*NGRP, 256, 0, stream>>>(ws+OFF_U2, ws+OFF_AC,
        ws+OFF_PH, ws+OFF_CP, ws+OFF_UG, ws+OFF_AG);
    k4c2<<<NB, 256, 0, stream>>>(ws+OFF_UG, ws+OFF_AG, ws+OFF_GH);
    k2b_fused<<<NB*NCH, 256, 0, stream>>>(ws+OFF_GT, ipw, ipb,
        Dv, norm_w, out_w, out_b,
        ws+OFF_PH, ws+OFF_CP, ws+OFF_GH, ws+OFF_ST, ws+OFF_G2);
    k5b_detok<<<NB*64, 64, 0, stream>>>(x, ws+OFF_G2, detok_w, detok_b, outp);
}